// Round 16
// baseline (368.805 us; speedup 1.0000x reference)
//
#include <hip/hip_runtime.h>
#include <hip/hip_cooperative_groups.h>
#include <math.h>

namespace cg = cooperative_groups;

#define CCH 256
#define HP2 68
#define WP2 68
#define NPIX 16384

typedef __attribute__((ext_vector_type(8))) short bf16x8;
typedef __attribute__((ext_vector_type(8))) unsigned short u16x8;
typedef __attribute__((ext_vector_type(4))) float f32x4;

__device__ __forceinline__ unsigned short f2bf(float f) {
    unsigned int u = __float_as_uint(f);
    unsigned int r = (u + 0x7fffu + ((u >> 16) & 1u)) >> 16;
    return (unsigned short)r;
}
__device__ __forceinline__ float bf2f(unsigned short h) {
    return __uint_as_float(((unsigned int)h) << 16);
}

__device__ __forceinline__ void gll16(const unsigned short* g, unsigned short* l) {
    __builtin_amdgcn_global_load_lds(
        (const __attribute__((address_space(1))) unsigned int*)g,
        (__attribute__((address_space(3))) unsigned int*)l,
        16, 0, 0);
}

// ---- workspace layout (bytes) ----
#define OFF_XNBF   0ull
#define OFF_XPAD   8388608ull
#define OFF_X1BF   17858560ull
#define OFF_OFFS   26247168ull
#define OFF_MASK   35684352ull
#define OFF_WTIN   40402944ull
#define OFF_WTOFF  40534016ull
#define OFF_WTMSK  40681472ull
#define OFF_BPAD   40755200ull
#define OFF_WTOUT  40796160ull
#define OFF_BOM    40927232ull
#define OFF_DWT    40928960ull

// ---- LDS-staged 128x128 MFMA GEMM tile (m97 structure) ----
template<int MODE>
__device__ __forceinline__ void gemm_tile(const unsigned short* __restrict__ A,
                                          const unsigned short* __restrict__ Bt,
                                          const float* __restrict__ bias,
                                          void* __restrict__ C0, void* __restrict__ C1,
                                          int N, int K, int bm, int bn, int tid,
                                          unsigned short* As, unsigned short* Bs) {
    int wid = tid >> 6, lane = tid & 63;
    int wr = wid >> 1, wc = wid & 1;
    int lr = lane & 15, kg = lane >> 4;
    int r = lane >> 2, q = lane & 3;

    const unsigned short* Ag0 = A + (size_t)(bm + 32 * wid + r) * K + q * 8;
    const unsigned short* Ag1 = Ag0 + (size_t)16 * K;
    const unsigned short* Bg0 = Bt + (size_t)(bn + 32 * wid + r) * K + q * 8;
    const unsigned short* Bg1 = Bg0 + (size_t)16 * K;
    unsigned short* Al0 = As + wid * 1024;
    unsigned short* Al1 = Al0 + 512;
    unsigned short* Bl0 = Bs + wid * 1024;
    unsigned short* Bl1 = Bl0 + 512;

    const unsigned short* Ar = As + (wr * 64 + lr) * 32 + kg * 8;
    const unsigned short* Br = Bs + (wc * 64 + lr) * 32 + kg * 8;

    f32x4 acc[4][4];
#pragma unroll
    for (int i = 0; i < 4; i++)
#pragma unroll
        for (int j = 0; j < 4; j++) acc[i][j] = (f32x4){0.f, 0.f, 0.f, 0.f};

    for (int k0 = 0; k0 < K; k0 += 32) {
        gll16(Ag0 + k0, Al0);
        gll16(Ag1 + k0, Al1);
        gll16(Bg0 + k0, Bl0);
        gll16(Bg1 + k0, Bl1);
        __syncthreads();
        bf16x8 a[4], b[4];
#pragma unroll
        for (int i = 0; i < 4; i++) a[i] = *(const bf16x8*)(Ar + i * 512);
#pragma unroll
        for (int j = 0; j < 4; j++) b[j] = *(const bf16x8*)(Br + j * 512);
        __builtin_amdgcn_s_setprio(1);
#pragma unroll
        for (int i = 0; i < 4; i++)
#pragma unroll
            for (int j = 0; j < 4; j++)
                acc[i][j] = __builtin_amdgcn_mfma_f32_16x16x32_bf16(a[i], b[j], acc[i][j], 0, 0, 0);
        __builtin_amdgcn_s_setprio(0);
        __syncthreads();
    }

    int row0 = bm + wr * 64, col0 = bn + wc * 64;
#pragma unroll
    for (int i = 0; i < 4; i++) {
#pragma unroll
        for (int j = 0; j < 4; j++) {
            int col = col0 + j * 16 + lr;
            if (col >= N) continue;
            float bc = (MODE == 4) ? 0.f : bias[col];
#pragma unroll
            for (int r2 = 0; r2 < 4; r2++) {
                int m = row0 + i * 16 + kg * 4 + r2;
                float val = acc[i][j][r2] + bc;
                if (MODE == 1) {
                    int n = m >> 12, hw = m & 4095, h = hw >> 6, w = hw & 63;
                    ((unsigned short*)C0)[(size_t)((n * HP2 + h + 2) * WP2 + (w + 2)) * CCH + col] = f2bf(val);
                } else if (MODE == 4) {
                    int n = col >> 12, hw = col & 4095;
                    ((float*)C0)[(size_t)(n * CCH + m) * 4096 + hw] = val + bias[m];
                } else {
                    if (col < 288)
                        ((unsigned short*)C0)[(size_t)m * 288 + col] = f2bf(val);
                    else
                        ((unsigned short*)C1)[(size_t)m * 144 + (col - 288)] = f2bf(val);
                }
            }
        }
    }
}

// single cooperative mega-kernel: 5 phases separated by grid.sync()
__global__ __launch_bounds__(256, 4) void mega(const float* __restrict__ x,
                                               const float* __restrict__ w_in,
                                               const float* __restrict__ b_in,
                                               const float* __restrict__ dw_w,
                                               const float* __restrict__ dw_b,
                                               const float* __restrict__ ln_g,
                                               const float* __restrict__ ln_b,
                                               const float* __restrict__ w_off,
                                               const float* __restrict__ b_off,
                                               const float* __restrict__ w_mask,
                                               const float* __restrict__ b_mask,
                                               const float* __restrict__ w_out,
                                               const float* __restrict__ b_out,
                                               float* __restrict__ out,
                                               char* __restrict__ ws) {
    unsigned short* xnbf  = (unsigned short*)(ws + OFF_XNBF);
    unsigned short* xpad  = (unsigned short*)(ws + OFF_XPAD);
    unsigned short* x1bf  = (unsigned short*)(ws + OFF_X1BF);
    unsigned short* offs  = (unsigned short*)(ws + OFF_OFFS);
    unsigned short* mkb   = (unsigned short*)(ws + OFF_MASK);
    unsigned short* wtin  = (unsigned short*)(ws + OFF_WTIN);
    unsigned short* wtoff = (unsigned short*)(ws + OFF_WTOFF);
    unsigned short* wtmsk = (unsigned short*)(ws + OFF_WTMSK);
    unsigned int*   bpad  = (unsigned int*)(ws + OFF_BPAD);
    unsigned short* wtout = (unsigned short*)(ws + OFF_WTOUT);
    float*          biasom = (float*)(ws + OFF_BOM);
    unsigned short* dwtb  = (unsigned short*)(ws + OFF_DWT);
    unsigned short* ybf   = xnbf;   // xnbf dead after phase 2
    unsigned int*   xpadz = (unsigned int*)xpad;

    __shared__ unsigned short As[4096];
    __shared__ unsigned short Bs[4096];
    cg::grid_group grid = cg::this_grid();
    int tid = threadIdx.x;
    int G = gridDim.x;
    int tx = tid & 31, ty = tid >> 5;

    // ---- P1: NCHW->NHWC bf16 + xpad ring-zero + wtin + dwtb ----
    for (int u = blockIdx.x; u < 4169; u += G) {
        __syncthreads();                       // protect LDS reuse across units
        if (u < 4096) {
            unsigned int i = (unsigned)u * 256 + tid;
            if (i < 270336u) {                 // ring-only zero (2112 border px x 128 uints)
                int rp = i >> 7, o = i & 127;
                int n = rp / 528, idx = rp % 528;
                int h, w;
                if (idx < 272) {
                    const int hr[4] = {0, 1, 66, 67};
                    h = hr[idx / 68]; w = idx % 68;
                } else {
                    int j = idx - 272;
                    const int wr4[4] = {0, 1, 66, 67};
                    h = 2 + (j >> 2); w = wr4[j & 3];
                }
                xpadz[(size_t)(n * (HP2 * WP2) + h * WP2 + w) * 128 + o] = 0u;
            }
            float* tt = (float*)As;            // 32x33 f32 scratch
            int hw0 = (u & 127) * 32, c0 = ((u >> 7) & 7) * 32, n = u >> 10;
#pragma unroll
            for (int i2 = 0; i2 < 4; i2++)
                tt[(ty + i2 * 8) * 33 + tx] = x[(size_t)(n * CCH + c0 + ty + i2 * 8) * 4096 + hw0 + tx];
            __syncthreads();
#pragma unroll
            for (int i2 = 0; i2 < 4; i2++)
                xnbf[(size_t)(n * 4096 + hw0 + ty + i2 * 8) * CCH + c0 + tx] = f2bf(tt[tx * 33 + ty + i2 * 8]);
        } else if (u < 4160) {
            int idx = u - 4096;                // wtin transpose, 64 units
            int n0 = (idx & 7) * 32, k0 = (idx >> 3) * 32;
            float* tb = (float*)As;
#pragma unroll
            for (int i = 0; i < 4; i++)
                tb[(ty + i * 8) * 33 + tx] = w_in[(size_t)(k0 + ty + i * 8) * 256 + n0 + tx];
            __syncthreads();
#pragma unroll
            for (int i = 0; i < 4; i++)
                wtin[(size_t)(n0 + ty + i * 8) * 256 + k0 + tx] = f2bf(tb[tx * 33 + ty + i * 8]);
        } else {
            int tap = u - 4160;                // dwtb, 9 units
            dwtb[tap * 256 + tid] = f2bf(dw_w[tid * 9 + tap]);
        }
    }
    grid.sync();

    // ---- P2: input_proj GEMM (256) | conv v4 (512) | deferred prep (218) ----
    for (int u = blockIdx.x; u < 986; u += G) {
        __syncthreads();
        if (u < 256) {
            gemm_tile<1>(xnbf, wtin, b_in, xpad, nullptr, 256, 256,
                         (u >> 1) * 128, (u & 1) * 128, tid, As, Bs);
        } else if (u < 768) {
            int cb = u - 256;
            int sb = (cb & 7) * 64 + (cb >> 3);
            int wid = tid >> 6, lane = tid & 63;
            int sub = lane >> 5, li = lane & 31;
            int mb = sb * 32 + wid * 8 + sub * 4;
            int n = mb >> 12, hw = mb & 4095, h = hw >> 6, w0 = hw & 63;
            int c0 = li << 3;
            float acc[4][8];
            {
                float4 b0 = *(const float4*)(dw_b + c0);
                float4 b1 = *(const float4*)(dw_b + c0 + 4);
                float bb[8] = {b0.x, b0.y, b0.z, b0.w, b1.x, b1.y, b1.z, b1.w};
#pragma unroll
                for (int j = 0; j < 4; j++)
#pragma unroll
                    for (int qq = 0; qq < 8; qq++) acc[j][qq] = bb[qq];
            }
            const u16x8 zz = {0, 0, 0, 0, 0, 0, 0, 0};
#pragma unroll
            for (int ky = 0; ky < 3; ky++) {
                int hy = h + ky - 1;
                if ((unsigned)hy >= 64u) continue;
                const unsigned short* rowp = xnbf + (size_t)(n * 4096 + hy * 64) * CCH + c0;
                u16x8 tap[6];
#pragma unroll
                for (int k6 = 0; k6 < 6; k6++) {
                    int wx = w0 + k6 - 1;
                    tap[k6] = ((unsigned)wx < 64u) ? *(const u16x8*)(rowp + (size_t)wx * CCH) : zz;
                }
                u16x8 wv[3];
#pragma unroll
                for (int kx = 0; kx < 3; kx++)
                    wv[kx] = *(const u16x8*)(dwtb + (ky * 3 + kx) * CCH + c0);
#pragma unroll
                for (int j = 0; j < 4; j++)
#pragma unroll
                    for (int kx = 0; kx < 3; kx++)
#pragma unroll
                        for (int qq = 0; qq < 8; qq++)
                            acc[j][qq] += bf2f(tap[j + kx][qq]) * bf2f(wv[kx][qq]);
            }
            float s[4], s2[4];
#pragma unroll
            for (int j = 0; j < 4; j++) {
                s[j] = 0.f; s2[j] = 0.f;
#pragma unroll
                for (int qq = 0; qq < 8; qq++) { s[j] += acc[j][qq]; s2[j] += acc[j][qq] * acc[j][qq]; }
            }
#pragma unroll
            for (int off = 16; off; off >>= 1) {
#pragma unroll
                for (int j = 0; j < 4; j++) {
                    s[j] += __shfl_xor(s[j], off);
                    s2[j] += __shfl_xor(s2[j], off);
                }
            }
            float4 g0 = *(const float4*)(ln_g + c0);
            float4 g1 = *(const float4*)(ln_g + c0 + 4);
            float4 bb0 = *(const float4*)(ln_b + c0);
            float4 bb1 = *(const float4*)(ln_b + c0 + 4);
            float gg[8] = {g0.x, g0.y, g0.z, g0.w, g1.x, g1.y, g1.z, g1.w};
            float bbv[8] = {bb0.x, bb0.y, bb0.z, bb0.w, bb1.x, bb1.y, bb1.z, bb1.w};
            const float is2 = 0.70710678118654752f;
#pragma unroll
            for (int j = 0; j < 4; j++) {
                float mean = s[j] * (1.f / 256.f);
                float var = s2[j] * (1.f / 256.f) - mean * mean;
                float rstd = 1.f / sqrtf(var + 1e-5f);
                u16x8 o;
#pragma unroll
                for (int qq = 0; qq < 8; qq++) {
                    float gv = (acc[j][qq] - mean) * rstd * gg[qq] + bbv[qq];
                    o[qq] = f2bf(0.5f * gv * (1.f + erff(gv * is2)));
                }
                *(u16x8*)(x1bf + (size_t)(mb + j) * CCH + c0) = o;
            }
        } else {
            int b = u - 768;
            if (b < 176) {
                const float* w; unsigned short* wt; int N, nb, idx;
                if (b < 72)       { w = w_off;  wt = wtoff; N = 288; nb = 9; idx = b; }
                else if (b < 112) { w = w_mask; wt = wtmsk; N = 144; nb = 5; idx = b - 72; }
                else              { w = w_out;  wt = wtout; N = 256; nb = 8; idx = b - 112; }
                int n0 = (idx % nb) * 32, k0 = (idx / nb) * 32;
                float* tb = (float*)As;
#pragma unroll
                for (int i = 0; i < 4; i++) {
                    int k = k0 + ty + i * 8;
                    if (n0 + tx < N) tb[(ty + i * 8) * 33 + tx] = w[(size_t)k * N + n0 + tx];
                }
                __syncthreads();
#pragma unroll
                for (int i = 0; i < 4; i++) {
                    int n = n0 + ty + i * 8;
                    if (n < N) wt[(size_t)n * 256 + k0 + tx] = f2bf(tb[tx * 33 + ty + i * 8]);
                }
            } else if (b < 178) {
                int i = (b - 176) * 256 + tid;
                if (i < 432) biasom[i] = (i < 288) ? b_off[i] : b_mask[i - 288];
            } else {
                bpad[(size_t)(b - 178) * 256 + tid] = 0u;
            }
        }
    }
    grid.sync();

    // ---- P3: offset+mask GEMM (512 units) ----
    for (int u = blockIdx.x; u < 512; u += G) {
        __syncthreads();
        gemm_tile<5>(x1bf, wtoff, biasom, offs, mkb, 432, 256,
                     (u >> 2) * 128, (u & 3) * 128, tid, As, Bs);
    }
    grid.sync();

    // ---- P4: DCNv3 core + fused softmax (2048 units, scatter, XCD-swizzled) ----
    for (int u0 = blockIdx.x; u0 < 2048; u0 += G) {
        int sb = (u0 & 7) * 256 + (u0 >> 3);
        int t = sb * 256 + tid;
        int half = t & 1, g = (t >> 1) & 15, m = t >> 5;
        int n = m >> 12, hw = m & 4095, h = hw >> 6, w = hw & 63;
        const unsigned int* op32 = (const unsigned int*)(offs + (size_t)m * 288 + g * 18);
        const unsigned short* mp = mkb + ((size_t)m * 16 + g) * 9;
        const unsigned short* xb = xpad + (size_t)n * (HP2 * WP2 * CCH) + g * 16 + half * 8;

        float mv[9];
        float mx = -1e30f;
#pragma unroll
        for (int i = 0; i < 9; i++) { mv[i] = bf2f(mp[i]); mx = fmaxf(mx, mv[i]); }
        float s = 0.f;
#pragma unroll
        for (int i = 0; i < 9; i++) { mv[i] = expf(mv[i] - mx); s += mv[i]; }
        float rs = 1.f / s;

        float acc[8] = {0.f};
#pragma unroll
        for (int p = 0; p < 9; p++) {
            int dx = p / 3 - 1, dy = p % 3 - 1;
            unsigned int pk = op32[p];
            float ox = bf2f((unsigned short)(pk & 0xffffu));
            float oy = bf2f((unsigned short)(pk >> 16));
            float px = fminf(fmaxf((float)(w + 2 + dx) + ox, 0.f), 67.f);
            float py = fminf(fmaxf((float)(h + 2 + dy) + oy, 0.f), 67.f);
            float x0f = floorf(px), y0f = floorf(py);
            float fx = px - x0f, fy = py - y0f;
            int x0 = (int)x0f, y0 = (int)y0f;
            int x1c = min(x0 + 1, 67), y1c = min(y0 + 1, 67);
            float mval = mv[p] * rs;
            float w00 = (1.f - fx) * (1.f - fy) * mval;
            float w01 = fx * (1.f - fy) * mval;
            float w10 = (1.f - fx) * fy * mval;
            float w11 = fx * fy * mval;
            const unsigned short* r0 = xb + (size_t)y0 * (WP2 * CCH);
            const unsigned short* r1 = xb + (size_t)y1c * (WP2 * CCH);
            u16x8 v00 = *(const u16x8*)(r0 + x0 * CCH);
            u16x8 v01 = *(const u16x8*)(r0 + x1c * CCH);
            u16x8 v10 = *(const u16x8*)(r1 + x0 * CCH);
            u16x8 v11 = *(const u16x8*)(r1 + x1c * CCH);
#pragma unroll
            for (int qq = 0; qq < 8; qq++)
                acc[qq] += w00 * bf2f(v00[qq]) + w01 * bf2f(v01[qq])
                         + w10 * bf2f(v10[qq]) + w11 * bf2f(v11[qq]);
        }
        u16x8 v;
#pragma unroll
        for (int qq = 0; qq < 8; qq++) v[qq] = f2bf(acc[qq]);
        *(u16x8*)(ybf + (size_t)m * CCH + g * 16 + half * 8) = v;
    }
    grid.sync();

    // ---- P5: output_proj GEMM swapped -> NCHW f32 (256 units) ----
    for (int u = blockIdx.x; u < 256; u += G) {
        __syncthreads();
        gemm_tile<4>(wtout, ybf, b_out, out, nullptr, 16384, 256,
                     (u & 1) * 128, (u >> 1) * 128, tid, As, Bs);
    }
}

extern "C" void kernel_launch(void* const* d_in, const int* in_sizes, int n_in,
                              void* d_out, int out_size, void* d_ws, size_t ws_size,
                              hipStream_t stream) {
    const float* x      = (const float*)d_in[0];
    const float* w_in   = (const float*)d_in[1];
    const float* b_in   = (const float*)d_in[2];
    const float* dw_w   = (const float*)d_in[3];
    const float* dw_b   = (const float*)d_in[4];
    const float* ln_g   = (const float*)d_in[5];
    const float* ln_b   = (const float*)d_in[6];
    const float* w_off  = (const float*)d_in[7];
    const float* b_off  = (const float*)d_in[8];
    const float* w_mask = (const float*)d_in[9];
    const float* b_mask = (const float*)d_in[10];
    const float* w_out  = (const float*)d_in[11];
    const float* b_out  = (const float*)d_in[12];
    float* out = (float*)d_out;
    char* ws = (char*)d_ws;

    int maxb = 0;
    hipOccupancyMaxActiveBlocksPerMultiprocessor(&maxb, mega, 256, 0);
    if (maxb < 1) maxb = 1;
    int grid = maxb * 256;          // 256 CUs on MI355X
    if (grid > 1024) grid = 1024;

    void* args[] = {&x, &w_in, &b_in, &dw_w, &dw_b, &ln_g, &ln_b,
                    &w_off, &b_off, &w_mask, &b_mask, &w_out, &b_out, &out, &ws};
    hipLaunchCooperativeKernel(reinterpret_cast<void*>(mega), dim3(grid), dim3(256),
                               args, 0, stream);
}

// Round 17
// 77.081 us; speedup vs baseline: 4.7846x; 4.7846x over previous
//
#include <hip/hip_runtime.h>
#include <math.h>

#define CCH 256
#define HP2 68
#define WP2 68
#define NPIX 16384

typedef __attribute__((ext_vector_type(8))) short bf16x8;
typedef __attribute__((ext_vector_type(8))) unsigned short u16x8;
typedef __attribute__((ext_vector_type(4))) float f32x4;

__device__ __forceinline__ unsigned short f2bf(float f) {
    unsigned int u = __float_as_uint(f);
    unsigned int r = (u + 0x7fffu + ((u >> 16) & 1u)) >> 16;
    return (unsigned short)r;
}
__device__ __forceinline__ float bf2f(unsigned short h) {
    return __uint_as_float(((unsigned int)h) << 16);
}

// async global->LDS, 16B per lane; LDS dest is wave-uniform base + lane*16
__device__ __forceinline__ void gll16(const unsigned short* g, unsigned short* l) {
    __builtin_amdgcn_global_load_lds(
        (const __attribute__((address_space(1))) unsigned int*)g,
        (__attribute__((address_space(3))) unsigned int*)l,
        16, 0, 0);
}

// ---- workspace layout (bytes) ----
#define OFF_XNBF   0ull          // 16384*256 bf16 = 8,388,608  (reused as y_bf after stage2)
#define OFF_XPAD   8388608ull    // 4*68*68*256 bf16 = 9,469,952 (only border ring re-zeroed)
#define OFF_X1BF   17858560ull   // 16384*256 bf16 = 8,388,608
#define OFF_OFFS   26247168ull   // 16384*288 bf16 = 9,437,184
#define OFF_MASK   35684352ull   // 16384*144 bf16 = 4,718,592
#define OFF_WTIN   40402944ull   // 256*256 bf16   = 131,072
#define OFF_WTOFF  40534016ull   // 288*256 bf16   = 147,456   (wtoff+wtmsk+pad contiguous = 512xK)
#define OFF_WTMSK  40681472ull   // 144*256 bf16   = 73,728
#define OFF_BPAD   40755200ull   // 80*256 bf16    = 40,960   (zero pad rows 432..511)
#define OFF_WTOUT  40796160ull   // 256*256 bf16   = 131,072
#define OFF_BOM    40927232ull   // 432 f32        = 1,728
#define OFF_DWT    40928960ull   // 9*256 bf16     = 4,608  (depthwise w, tap-major)
// end = 40,933,568 bytes

// prep (minimal critical path): z<4 -> NCHW f32 -> NHWC bf16 (+ ring-zero xpad);
// z=4 -> wtin transpose; z=5 -> dwtb (tap-major depthwise weights)
__global__ __launch_bounds__(256) void prep(const float* __restrict__ x,
                                            unsigned short* __restrict__ xo,
                                            unsigned int* __restrict__ xpadz,
                                            const float* __restrict__ w_in,
                                            unsigned short* __restrict__ wtin,
                                            const float* __restrict__ dw_w,
                                            unsigned short* __restrict__ dwtb) {
    int z = blockIdx.z;
    int tx = threadIdx.x, ty = threadIdx.y;
    int t = ty * 32 + tx;
    if (z < 4) {
        // ring-only zero of xpad: 2112 border pixels x 128 uints = 270,336 uints
        int flat = (z * 8 + blockIdx.y) * 128 + blockIdx.x;   // 0..4095
        unsigned int i = flat * 256 + t;                      // 0..1048575
        if (i < 270336u) {
            int rp = i >> 7, o = i & 127;
            int n = rp / 528, idx = rp % 528;
            int h, w;
            if (idx < 272) {
                static const int hr[4] = {0, 1, 66, 67};
                h = hr[idx / 68]; w = idx % 68;
            } else {
                int j = idx - 272;
                static const int wr[4] = {0, 1, 66, 67};
                h = 2 + (j >> 2); w = wr[j & 3];
            }
            xpadz[(size_t)(n * (HP2 * WP2) + h * WP2 + w) * 128 + o] = 0u;
        }
        __shared__ float tt[32][33];
        int hw0 = blockIdx.x * 32, c0 = blockIdx.y * 32, n = z;
#pragma unroll
        for (int i2 = 0; i2 < 4; i2++)
            tt[ty + i2 * 8][tx] = x[(size_t)(n * CCH + c0 + ty + i2 * 8) * 4096 + hw0 + tx];
        __syncthreads();
#pragma unroll
        for (int i2 = 0; i2 < 4; i2++)
            xo[(size_t)(n * 4096 + hw0 + ty + i2 * 8) * CCH + c0 + tx] = f2bf(tt[tx][ty + i2 * 8]);
        return;
    }
    if (z == 4) {
        if (blockIdx.x >= 8) return;
        const int K = 256, N = 256;
        int n0 = blockIdx.x * 32, k0 = blockIdx.y * 32;
        __shared__ float tb[32][33];
#pragma unroll
        for (int i = 0; i < 4; i++)
            tb[ty + i * 8][tx] = w_in[(size_t)(k0 + ty + i * 8) * N + n0 + tx];
        __syncthreads();
#pragma unroll
        for (int i = 0; i < 4; i++)
            wtin[(size_t)(n0 + ty + i * 8) * K + k0 + tx] = f2bf(tb[tx][ty + i * 8]);
        return;
    }
    // z == 5: dwtb
    if (blockIdx.y == 0 && blockIdx.x < 9) {
        int tap = blockIdx.x;
        dwtb[tap * 256 + t] = f2bf(dw_w[t * 9 + tap]);
    }
}

// ---- LDS-staged 128x128 MFMA GEMM tile (m97 structure: BK=32, 2 barriers/k-step) ----
// MODE 1: bf16 scatter to padded 68x68 NHWC; MODE 4: f32 NCHW swapped (rows=channels);
// MODE 5: dual bf16 row-major (col<288 -> C0 ld288, else C1 ld144)
template<int MODE>
__device__ __forceinline__ void gemm_tile(const unsigned short* __restrict__ A,
                                          const unsigned short* __restrict__ Bt,
                                          const float* __restrict__ bias,
                                          void* __restrict__ C0, void* __restrict__ C1,
                                          int N, int K, int bm, int bn, int tid,
                                          unsigned short* As, unsigned short* Bs) {
    int wid = tid >> 6, lane = tid & 63;
    int wr = wid >> 1, wc = wid & 1;
    int lr = lane & 15, kg = lane >> 4;
    int r = lane >> 2, q = lane & 3;

    const unsigned short* Ag0 = A + (size_t)(bm + 32 * wid + r) * K + q * 8;
    const unsigned short* Ag1 = Ag0 + (size_t)16 * K;
    const unsigned short* Bg0 = Bt + (size_t)(bn + 32 * wid + r) * K + q * 8;
    const unsigned short* Bg1 = Bg0 + (size_t)16 * K;
    unsigned short* Al0 = As + wid * 1024;
    unsigned short* Al1 = Al0 + 512;
    unsigned short* Bl0 = Bs + wid * 1024;
    unsigned short* Bl1 = Bl0 + 512;

    const unsigned short* Ar = As + (wr * 64 + lr) * 32 + kg * 8;
    const unsigned short* Br = Bs + (wc * 64 + lr) * 32 + kg * 8;

    f32x4 acc[4][4];
#pragma unroll
    for (int i = 0; i < 4; i++)
#pragma unroll
        for (int j = 0; j < 4; j++) acc[i][j] = (f32x4){0.f, 0.f, 0.f, 0.f};

    for (int k0 = 0; k0 < K; k0 += 32) {
        gll16(Ag0 + k0, Al0);
        gll16(Ag1 + k0, Al1);
        gll16(Bg0 + k0, Bl0);
        gll16(Bg1 + k0, Bl1);
        __syncthreads();
        bf16x8 a[4], b[4];
#pragma unroll
        for (int i = 0; i < 4; i++) a[i] = *(const bf16x8*)(Ar + i * 512);
#pragma unroll
        for (int j = 0; j < 4; j++) b[j] = *(const bf16x8*)(Br + j * 512);
        __builtin_amdgcn_s_setprio(1);
#pragma unroll
        for (int i = 0; i < 4; i++)
#pragma unroll
            for (int j = 0; j < 4; j++)
                acc[i][j] = __builtin_amdgcn_mfma_f32_16x16x32_bf16(a[i], b[j], acc[i][j], 0, 0, 0);
        __builtin_amdgcn_s_setprio(0);
        __syncthreads();
    }

    int row0 = bm + wr * 64, col0 = bn + wc * 64;
#pragma unroll
    for (int i = 0; i < 4; i++) {
#pragma unroll
        for (int j = 0; j < 4; j++) {
            int col = col0 + j * 16 + lr;
            if (col >= N) continue;
            float bc = (MODE == 4) ? 0.f : bias[col];
#pragma unroll
            for (int r2 = 0; r2 < 4; r2++) {
                int m = row0 + i * 16 + kg * 4 + r2;
                float val = acc[i][j][r2] + bc;
                if (MODE == 1) {
                    int n = m >> 12, hw = m & 4095, h = hw >> 6, w = hw & 63;
                    ((unsigned short*)C0)[(size_t)((n * HP2 + h + 2) * WP2 + (w + 2)) * CCH + col] = f2bf(val);
                } else if (MODE == 4) {
                    int n = col >> 12, hw = col & 4095;
                    ((float*)C0)[(size_t)(n * CCH + m) * 4096 + hw] = val + bias[m];
                } else {
                    if (col < 288)
                        ((unsigned short*)C0)[(size_t)m * 288 + col] = f2bf(val);
                    else
                        ((unsigned short*)C1)[(size_t)m * 144 + (col - 288)] = f2bf(val);
                }
            }
        }
    }
}

template<int MODE>
__global__ __launch_bounds__(256) void gemm_mfma(const unsigned short* __restrict__ A,
                                                 const unsigned short* __restrict__ Bt,
                                                 const float* __restrict__ bias,
                                                 void* __restrict__ C0,
                                                 void* __restrict__ C1,
                                                 int N, int K) {
    __shared__ unsigned short As[4096];
    __shared__ unsigned short Bs[4096];
    gemm_tile<MODE>(A, Bt, bias, C0, C1, N, K, blockIdx.y * 128, blockIdx.x * 128,
                    threadIdx.x, As, Bs);
}

// stage2: [0,256) input_proj GEMM; [256,768) conv+LN+GELU;
// [768,986) deferred prep work (wtoff/wtmsk/wtout transposes, biasom, bpad)
__global__ __launch_bounds__(256) void stage2(const unsigned short* __restrict__ xnbf,
                                              const unsigned short* __restrict__ wtin,
                                              const float* __restrict__ b_in,
                                              unsigned short* __restrict__ xpad,
                                              const unsigned short* __restrict__ dwtb,
                                              const float* __restrict__ dw_b,
                                              const float* __restrict__ ln_g,
                                              const float* __restrict__ ln_b,
                                              unsigned short* __restrict__ x1,
                                              const float* __restrict__ w_off,
                                              const float* __restrict__ w_mask,
                                              const float* __restrict__ w_out,
                                              unsigned short* __restrict__ wtoff,
                                              unsigned short* __restrict__ wtmsk,
                                              unsigned short* __restrict__ wtout,
                                              const float* __restrict__ b_off,
                                              const float* __restrict__ b_mask,
                                              float* __restrict__ biasom,
                                              unsigned int* __restrict__ bpad) {
    __shared__ unsigned short As[4096];
    __shared__ unsigned short Bs[4096];
    int bid = blockIdx.x;
    if (bid < 256) {
        gemm_tile<1>(xnbf, wtin, b_in, xpad, nullptr, 256, 256,
                     (bid >> 1) * 128, (bid & 1) * 128, threadIdx.x, As, Bs);
        return;
    }
    if (bid < 768) {
        int cb = bid - 256;                          // 0..511
        int sb = (cb & 7) * 64 + (cb >> 3);          // XCD chunk swizzle (512 % 8 == 0)
        int wid = threadIdx.x >> 6, lane = threadIdx.x & 63;
        int sub = lane >> 5, li = lane & 31;
        int mb = sb * 32 + wid * 8 + sub * 4;        // 4 consecutive pixels (aligned run)
        int n = mb >> 12, hw = mb & 4095, h = hw >> 6, w0 = hw & 63;   // w0 % 4 == 0
        int c0 = li << 3;

        float acc[4][8];
        {
            float4 b0 = *(const float4*)(dw_b + c0);
            float4 b1 = *(const float4*)(dw_b + c0 + 4);
            float bb[8] = {b0.x, b0.y, b0.z, b0.w, b1.x, b1.y, b1.z, b1.w};
#pragma unroll
            for (int j = 0; j < 4; j++)
#pragma unroll
                for (int q = 0; q < 8; q++) acc[j][q] = bb[q];
        }
        const u16x8 zz = {0, 0, 0, 0, 0, 0, 0, 0};
#pragma unroll
        for (int ky = 0; ky < 3; ky++) {
            int hy = h + ky - 1;
            if ((unsigned)hy >= 64u) continue;
            const unsigned short* rowp = xnbf + (size_t)(n * 4096 + hy * 64) * CCH + c0;
            u16x8 tap[6];
#pragma unroll
            for (int k6 = 0; k6 < 6; k6++) {
                int wx = w0 + k6 - 1;
                tap[k6] = ((unsigned)wx < 64u) ? *(const u16x8*)(rowp + (size_t)wx * CCH) : zz;
            }
            u16x8 wv[3];
#pragma unroll
            for (int kx = 0; kx < 3; kx++)
                wv[kx] = *(const u16x8*)(dwtb + (ky * 3 + kx) * CCH + c0);
#pragma unroll
            for (int j = 0; j < 4; j++)
#pragma unroll
                for (int kx = 0; kx < 3; kx++)
#pragma unroll
                    for (int q = 0; q < 8; q++)
                        acc[j][q] += bf2f(tap[j + kx][q]) * bf2f(wv[kx][q]);
        }
        float s[4], s2[4];
#pragma unroll
        for (int j = 0; j < 4; j++) {
            s[j] = 0.f; s2[j] = 0.f;
#pragma unroll
            for (int q = 0; q < 8; q++) { s[j] += acc[j][q]; s2[j] += acc[j][q] * acc[j][q]; }
        }
#pragma unroll
        for (int off = 16; off; off >>= 1) {         // masks <32: stays within each 32-lane half
#pragma unroll
            for (int j = 0; j < 4; j++) {
                s[j] += __shfl_xor(s[j], off);
                s2[j] += __shfl_xor(s2[j], off);
            }
        }
        float4 g0 = *(const float4*)(ln_g + c0);
        float4 g1 = *(const float4*)(ln_g + c0 + 4);
        float4 bb0 = *(const float4*)(ln_b + c0);
        float4 bb1 = *(const float4*)(ln_b + c0 + 4);
        float gg[8] = {g0.x, g0.y, g0.z, g0.w, g1.x, g1.y, g1.z, g1.w};
        float bbv[8] = {bb0.x, bb0.y, bb0.z, bb0.w, bb1.x, bb1.y, bb1.z, bb1.w};
        const float is2 = 0.70710678118654752f;
#pragma unroll
        for (int j = 0; j < 4; j++) {
            float mean = s[j] * (1.f / 256.f);
            float var = s2[j] * (1.f / 256.f) - mean * mean;
            float rstd = 1.f / sqrtf(var + 1e-5f);
            u16x8 o;
#pragma unroll
            for (int q = 0; q < 8; q++) {
                float gv = (acc[j][q] - mean) * rstd * gg[q] + bbv[q];
                o[q] = f2bf(0.5f * gv * (1.f + erff(gv * is2)));
            }
            *(u16x8*)(x1 + (size_t)(mb + j) * CCH + c0) = o;
        }
        return;
    }
    // deferred prep work
    int b = bid - 768;
    int t = threadIdx.x;
    int tx = t & 31, ty = t >> 5;
    if (b < 176) {
        const float* w; unsigned short* wt; int N, nb, idx;
        if (b < 72)       { w = w_off;  wt = wtoff; N = 288; nb = 9; idx = b; }
        else if (b < 112) { w = w_mask; wt = wtmsk; N = 144; nb = 5; idx = b - 72; }
        else              { w = w_out;  wt = wtout; N = 256; nb = 8; idx = b - 112; }
        const int K = 256;
        int n0 = (idx % nb) * 32, k0 = (idx / nb) * 32;
        float* tb = (float*)As;   // reuse GEMM LDS as 32x33 f32 scratch
#pragma unroll
        for (int i = 0; i < 4; i++) {
            int k = k0 + ty + i * 8;
            if (n0 + tx < N) tb[(ty + i * 8) * 33 + tx] = w[(size_t)k * N + n0 + tx];
        }
        __syncthreads();
#pragma unroll
        for (int i = 0; i < 4; i++) {
            int n = n0 + ty + i * 8;
            if (n < N) wt[(size_t)n * K + k0 + tx] = f2bf(tb[tx * 33 + ty + i * 8]);
        }
    } else if (b < 178) {
        int i = (b - 176) * 256 + t;
        if (i < 432) biasom[i] = (i < 288) ? b_off[i] : b_mask[i - 288];
    } else {
        bpad[(size_t)(b - 178) * 256 + t] = 0u;   // 40 blocks x 256 = 10240 uints
    }
}

// DCNv3 core + fused mask softmax, branchless via 2-ring pad + coord clamp.
// one thread per (pixel, group, channel-half); 2048 blocks XCD-swizzled
__global__ __launch_bounds__(256) void dcn_core(const unsigned short* __restrict__ xpad,
                                                const unsigned short* __restrict__ offs,
                                                const unsigned short* __restrict__ mk,
                                                unsigned short* __restrict__ y) {
    int bid = blockIdx.x;
    int sb = (bid & 7) * 256 + (bid >> 3);
    int t = sb * 256 + threadIdx.x;          // 0 .. 524287
    int half = t & 1, g = (t >> 1) & 15, m = t >> 5;
    int n = m >> 12, hw = m & 4095, h = hw >> 6, w = hw & 63;
    const unsigned int* op32 = (const unsigned int*)(offs + (size_t)m * 288 + g * 18);
    const unsigned short* mp = mk + ((size_t)m * 16 + g) * 9;
    const unsigned short* xb = xpad + (size_t)n * (HP2 * WP2 * CCH) + g * 16 + half * 8;

    float mv[9];
    float mx = -1e30f;
#pragma unroll
    for (int i = 0; i < 9; i++) { mv[i] = bf2f(mp[i]); mx = fmaxf(mx, mv[i]); }
    float s = 0.f;
#pragma unroll
    for (int i = 0; i < 9; i++) { mv[i] = expf(mv[i] - mx); s += mv[i]; }
    float rs = 1.f / s;

    float acc[8] = {0.f};
#pragma unroll
    for (int p = 0; p < 9; p++) {
        int dx = p / 3 - 1, dy = p % 3 - 1;
        unsigned int pk = op32[p];
        float ox = bf2f((unsigned short)(pk & 0xffffu));
        float oy = bf2f((unsigned short)(pk >> 16));
        float px = fminf(fmaxf((float)(w + 2 + dx) + ox, 0.f), 67.f);
        float py = fminf(fmaxf((float)(h + 2 + dy) + oy, 0.f), 67.f);
        float x0f = floorf(px), y0f = floorf(py);
        float fx = px - x0f, fy = py - y0f;
        int x0 = (int)x0f, y0 = (int)y0f;
        int x1c = min(x0 + 1, 67), y1c = min(y0 + 1, 67);
        float mval = mv[p] * rs;
        float w00 = (1.f - fx) * (1.f - fy) * mval;
        float w01 = fx * (1.f - fy) * mval;
        float w10 = (1.f - fx) * fy * mval;
        float w11 = fx * fy * mval;
        const unsigned short* r0 = xb + (size_t)y0 * (WP2 * CCH);
        const unsigned short* r1 = xb + (size_t)y1c * (WP2 * CCH);
        u16x8 v00 = *(const u16x8*)(r0 + x0 * CCH);
        u16x8 v01 = *(const u16x8*)(r0 + x1c * CCH);
        u16x8 v10 = *(const u16x8*)(r1 + x0 * CCH);
        u16x8 v11 = *(const u16x8*)(r1 + x1c * CCH);
#pragma unroll
        for (int q = 0; q < 8; q++)
            acc[q] += w00 * bf2f(v00[q]) + w01 * bf2f(v01[q])
                    + w10 * bf2f(v10[q]) + w11 * bf2f(v11[q]);
    }
    u16x8 v;
#pragma unroll
    for (int q = 0; q < 8; q++) v[q] = f2bf(acc[q]);
    *(u16x8*)(y + (size_t)m * CCH + g * 16 + half * 8) = v;
}

extern "C" void kernel_launch(void* const* d_in, const int* in_sizes, int n_in,
                              void* d_out, int out_size, void* d_ws, size_t ws_size,
                              hipStream_t stream) {
    const float* x      = (const float*)d_in[0];
    const float* w_in   = (const float*)d_in[1];
    const float* b_in   = (const float*)d_in[2];
    const float* dw_w   = (const float*)d_in[3];
    const float* dw_b   = (const float*)d_in[4];
    const float* ln_g   = (const float*)d_in[5];
    const float* ln_b   = (const float*)d_in[6];
    const float* w_off  = (const float*)d_in[7];
    const float* b_off  = (const float*)d_in[8];
    const float* w_mask = (const float*)d_in[9];
    const float* b_mask = (const float*)d_in[10];
    const float* w_out  = (const float*)d_in[11];
    const float* b_out  = (const float*)d_in[12];
    float* out = (float*)d_out;
    char* ws = (char*)d_ws;

    unsigned short* xnbf  = (unsigned short*)(ws + OFF_XNBF);
    unsigned short* xpad  = (unsigned short*)(ws + OFF_XPAD);
    unsigned short* x1bf  = (unsigned short*)(ws + OFF_X1BF);
    unsigned short* offs  = (unsigned short*)(ws + OFF_OFFS);
    unsigned short* mkb   = (unsigned short*)(ws + OFF_MASK);
    unsigned short* wtin  = (unsigned short*)(ws + OFF_WTIN);
    unsigned short* wtoff = (unsigned short*)(ws + OFF_WTOFF);
    unsigned short* wtmsk = (unsigned short*)(ws + OFF_WTMSK);
    unsigned int*   bpad  = (unsigned int*)(ws + OFF_BPAD);
    unsigned short* wtout = (unsigned short*)(ws + OFF_WTOUT);
    float*          biasom = (float*)(ws + OFF_BOM);
    unsigned short* dwtb  = (unsigned short*)(ws + OFF_DWT);
    unsigned short* ybf   = xnbf;   // xnbf dead after stage2

    // 1. minimal prep: transpose + ring-zero + wtin + dwtb
    prep<<<dim3(128, 8, 6), dim3(32, 8), 0, stream>>>(x, xnbf, (unsigned int*)xpad,
                                                      w_in, wtin, dw_w, dwtb);
    // 2. fused: input_proj GEMM (256) || conv v4 (512) || deferred prep (218)
    stage2<<<986, 256, 0, stream>>>(xnbf, wtin, b_in, xpad, dwtb, dw_b, ln_g, ln_b, x1bf,
                                    w_off, w_mask, w_out, wtoff, wtmsk, wtout,
                                    b_off, b_mask, biasom, bpad);
    // 3. fused offset+mask GEMM (N=432, B padded to 512 rows, dual bf16 out)
    gemm_mfma<5><<<dim3(4, 128), 256, 0, stream>>>(x1bf, wtoff, biasom, offs, mkb, 432, 256);
    // 4. DCNv3 core + fused softmax (branchless, XCD-swizzled)
    dcn_core<<<2048, 256, 0, stream>>>(xpad, offs, mkb, ybf);
    // 5. output_proj GEMM, swapped (rows=channels) -> coalesced NCHW f32
    gemm_mfma<4><<<dim3(128, 2), 256, 0, stream>>>(wtout, ybf, b_out, out, nullptr, 16384, 256);
}